// Round 11
// baseline (412.443 us; speedup 1.0000x reference)
//
#include <hip/hip_runtime.h>
#include <hip/hip_cooperative_groups.h>
#include <hip/hip_bf16.h>

namespace cg = cooperative_groups;

#define S_DIM 4
#define N_PTS 4096
#define P_TOT (S_DIM * N_PTS)   // 16384
#define KNB 16

#define GD 16                    // grid dim per axis
#define NCELL (GD * GD * GD)     // 4096
#define CSTRIDE (NCELL + 1)
#define CAP 224                  // per-wave candidate buffer
#define MAPSZ 512                // per-wave gather source map
#define NBLK 512
#define NTHR 512
#define PROJ_BLKS 256            // fallback pre_kernel: 64 pts/block

__device__ __forceinline__ float readlane_f(float v, int lane) {
    return __uint_as_float(__builtin_amdgcn_readlane(__float_as_uint(v), lane));
}

// ==================== shared helpers (device) ====================

struct SGB { int cnt[NCELL]; int start[NCELL + 1]; int wtot[8]; };   // 32.8 KB
struct SPJ { float xs[32][64]; float psf[96]; };                     // 8.6 KB
struct SAT {                                                          // 25 KB
    unsigned long long buf[8][CAP];
    unsigned short map[8][MAPSZ];
    int ridx[8][KNB];
    float ohs[8][64];
};
union SU { SGB gb; SPJ pj; SAT at; };

// Per-query exact KNN + attention body (used by both coop stage B and the
// fallback kernel). All LDS pointers are wave-private slices.
__device__ __forceinline__ void knn_attn_query(
    int qslot, int lane,
    unsigned long long* mybuf, unsigned short* mymap, int* myridx, float* myohs,
    const float* __restrict__ x, const float* __restrict__ pos,
    const int* __restrict__ cell_start, const float4* __restrict__ gpts,
    float wpd0, float wpd1, float wpd2, float bpdh,
    float wa, float ba0, float boh,
    const float* __restrict__ Wo,
    const float* __restrict__ qpe, const float* __restrict__ kpe,
    const float* __restrict__ vv, float* __restrict__ out)
{
    int s = qslot >> 12;
    int sbase = s << 12;
    const int* cs = cell_start + s * CSTRIDE;
    const float4* gp = gpts + (size_t)sbase;

    float4 q4 = gp[qslot & (N_PTS - 1)];
    float qx = q4.x, qy = q4.y, qz = q4.z;
    int g = sbase + (int)__float_as_uint(q4.w);

    // early-issue phase-2 operands
    float qv   = qpe[g * 64 + lane];
    float xres = x[g * 64 + lane];

    // adaptive radius: target ~32 candidates incl. boundary truncation
    float bx = fminf(qx, 1.f - qx), by = fminf(qy, 1.f - qy), bz = fminf(qz, 1.f - qz);
    float r = 0.125f;
    #pragma unroll
    for (int it = 0; it < 2; ++it) {
        float ux = fminf(bx / r, 1.f), uy = fminf(by / r, 1.f), uz = fminf(bz / r, 1.f);
        float fx = 0.5f + 0.75f * ux - 0.25f * ux * ux * ux;
        float fy = 0.5f + 0.75f * uy - 0.25f * uy * uy * uy;
        float fz = 0.5f + 0.75f * uz - 0.25f * uz * uz * uz;
        float est = 17157.3f * r * r * r * fx * fy * fz;
        float sc = exp2f(0.3333333f * log2f(32.f / est));
        r = fminf(fmaxf(r * sc, 0.09f), 0.32f);
    }
    r = __uint_as_float(__builtin_amdgcn_readfirstlane(__float_as_uint(r)));

    unsigned long long lanemask_lt = (lane == 0) ? 0ull : (~0ull >> (64 - lane));

    int cnt = 0;
    for (int tries = 0; tries < 6; ++tries) {
        float B = r * r;
        float Bc = B * 1.0002f + 1e-7f;
        int xlo = max(0, (int)floorf((qx - r) * 16.f - 1e-4f));
        int xhi = min(GD - 1, (int)floorf((qx + r) * 16.f + 1e-4f));
        int ylo = max(0, (int)floorf((qy - r) * 16.f - 1e-4f));
        int yhi = min(GD - 1, (int)floorf((qy + r) * 16.f + 1e-4f));
        int nx = xhi - xlo + 1, ny = yhi - ylo + 1;
        int NC = __builtin_amdgcn_readfirstlane(nx * ny);
        float rcp_ny = 1.f / (float)ny;

        // protect previous map/buf reads before rewriting
        __builtin_amdgcn_wave_barrier();
        asm volatile("s_waitcnt lgkmcnt(0)" ::: "memory");

        // wave-parallel run-table -> direct source map
        int carry = 0;
        for (int c0 = 0; c0 < NC; c0 += 64) {
            int cidx = c0 + lane;
            bool vld = cidx < NC;
            int qd = (int)(((float)cidx + 0.5f) * rcp_ny);
            int iy = ylo + (cidx - qd * ny);
            int ix = xlo + qd;
            float x0 = (float)ix * 0.0625f;
            float ax = fmaxf(0.f, fmaxf(x0 - qx, qx - (x0 + 0.0625f)));
            float y0 = (float)iy * 0.0625f;
            float ay = fmaxf(0.f, fmaxf(y0 - qy, qy - (y0 + 0.0625f)));
            float rem = Bc - ax * ax - ay * ay;
            int lo = 0, len = 0;
            if (vld && rem > 0.f) {
                float zs = sqrtf(rem) + 1e-4f;
                int zl = max(0, (int)floorf((qz - zs) * 16.f));
                int zh = min(GD - 1, (int)floorf((qz + zs) * 16.f));
                int cb = (ix * GD + iy) * GD;
                lo = cs[cb + zl];
                len = cs[cb + zh + 1] - lo;
            }
            int inc2 = len;
            #pragma unroll
            for (int off = 1; off < 64; off <<= 1) {
                int n = __shfl_up(inc2, off, 64);
                if (lane >= off) inc2 += n;
            }
            int excl = carry + inc2 - len;
            for (int i = 0; i < len; ++i) {
                int d = excl + i;
                if (d < MAPSZ) mymap[d] = (unsigned short)(lo + i);
            }
            carry += __builtin_amdgcn_readlane(inc2, 63);
        }
        int T = carry;
        if (T > MAPSZ) { r = r * 0.72f; continue; }

        __builtin_amdgcn_wave_barrier();
        asm volatile("s_waitcnt lgkmcnt(0)" ::: "memory");

        // gather + compact
        cnt = 0;
        for (int p0 = 0; p0 < T; p0 += 64) {
            int pidx = p0 + lane;
            bool act = pidx < T;
            int src = mymap[act ? pidx : 0];
            float4 p = gp[src];
            float dx = qx - p.x, dy = qy - p.y, dz = qz - p.z;
            float d = fmaf(dx, dx, fmaf(dy, dy, dz * dz));
            bool pred = act && (d < B);
            unsigned long long m = __ballot(pred);
            if (pred) {
                int slot = cnt + __popcll(m & lanemask_lt);
                if (slot < CAP)
                    mybuf[slot] =
                        ((unsigned long long)__float_as_uint(d) << 32) |
                        (unsigned long long)__float_as_uint(p.w);
            }
            cnt += __popcll(m);
        }
        if (cnt >= KNB && cnt <= CAP) break;
        r = (cnt < KNB) ? r * 1.35f : r * 0.72f;
    }
    cnt = min(cnt, CAP);

    __builtin_amdgcn_wave_barrier();
    asm volatile("s_waitcnt lgkmcnt(0)" ::: "memory");

    // rank-count selection (exact jax.lax.top_k order)
    if (lane < KNB) myridx[lane] = 0;
    for (int bb = 0; bb < cnt; bb += 64) {
        int slot = bb + lane;
        unsigned long long my = (slot < cnt) ? mybuf[slot] : ~0ull;
        int rank = 0;
        for (int j = 0; j < cnt; ++j)
            rank += (mybuf[j] < my) ? 1 : 0;
        if (slot < cnt && rank < KNB)
            myridx[rank] = (int)(unsigned)(my & 0xFFFFFFFFull);
    }
    __builtin_amdgcn_wave_barrier();
    asm volatile("s_waitcnt lgkmcnt(0)" ::: "memory");
    int res = (lane < KNB) ? myridx[lane] : 0;

    // ---- attention (lane = h)
    int h = lane;
    float wh = qv * wa * 0.125f;   // / sqrt(64)

    int jidx[KNB];
    float t[KNB];
    #pragma unroll
    for (int k = 0; k < KNB; ++k) {
        int jj = sbase + __builtin_amdgcn_readlane(res, k);
        jidx[k] = jj;
        float rx = pos[jj * 3 + 0] - qx;
        float ry = pos[jj * 3 + 1] - qy;
        float rz = pos[jj * 3 + 2] - qz;
        float pd = fmaf(rx, wpd0, fmaf(ry, wpd1, fmaf(rz, wpd2, bpdh)));
        t[k] = wh * (kpe[jj * 64 + h] + pd);
    }

    // merged log-tree reduction: 16 vectors with 31 shfl
    #pragma unroll
    for (int kk = 0; kk < 8; ++kk) {
        float a = t[2 * kk]     + __shfl_xor(t[2 * kk],     32, 64);
        float b = t[2 * kk + 1] + __shfl_xor(t[2 * kk + 1], 32, 64);
        t[kk] = (h & 32) ? b : a;
    }
    #pragma unroll
    for (int kk = 0; kk < 4; ++kk) {
        float a = t[2 * kk]     + __shfl_xor(t[2 * kk],     16, 64);
        float b = t[2 * kk + 1] + __shfl_xor(t[2 * kk + 1], 16, 64);
        t[kk] = (h & 16) ? b : a;
    }
    #pragma unroll
    for (int kk = 0; kk < 2; ++kk) {
        float a = t[2 * kk]     + __shfl_xor(t[2 * kk],     8, 64);
        float b = t[2 * kk + 1] + __shfl_xor(t[2 * kk + 1], 8, 64);
        t[kk] = (h & 8) ? b : a;
    }
    {
        float a = t[0] + __shfl_xor(t[0], 4, 64);
        float b = t[1] + __shfl_xor(t[1], 4, 64);
        t[0] = (h & 4) ? b : a;
    }
    float rr = t[0];
    rr += __shfl_xor(rr, 2, 64);
    rr += __shfl_xor(rr, 1, 64);
    // lane holds logit of k = rev4(lane>>2)

    float lg = rr + ba0;
    float mx = lg;
    mx = fmaxf(mx, __shfl_xor(mx, 4, 64));
    mx = fmaxf(mx, __shfl_xor(mx, 8, 64));
    mx = fmaxf(mx, __shfl_xor(mx, 16, 64));
    mx = fmaxf(mx, __shfl_xor(mx, 32, 64));
    float e = expf(lg - mx);
    float sm = e;
    sm += __shfl_xor(sm, 4, 64);
    sm += __shfl_xor(sm, 8, 64);
    sm += __shfl_xor(sm, 16, 64);
    sm += __shfl_xor(sm, 32, 64);
    float wk_mine = e * (1.0f / sm);

    // PV: broadcast w_k from lane rev4(k)*4 (rev4 is an involution)
    const int rev[KNB] = {0, 8, 4, 12, 2, 10, 6, 14, 1, 9, 5, 13, 3, 11, 7, 15};
    float oh = 0.f;
    #pragma unroll
    for (int k = 0; k < KNB; ++k) {
        float wk = readlane_f(wk_mine, rev[k] << 2);
        oh = fmaf(wk, vv[jidx[k] * 64 + h], oh);
    }

    // Wo projection via LDS float4 broadcast reads
    myohs[h] = oh;
    __builtin_amdgcn_wave_barrier();
    asm volatile("s_waitcnt lgkmcnt(0)" ::: "memory");
    const float4* oh4 = (const float4*)myohs;
    float yy0 = boh, yy1 = 0.f;
    #pragma unroll
    for (int i = 0; i < 16; ++i) {
        float4 o = oh4[i];
        yy0 = fmaf(o.x, Wo[(4 * i + 0) * 64 + h], yy0);
        yy1 = fmaf(o.y, Wo[(4 * i + 1) * 64 + h], yy1);
        yy0 = fmaf(o.z, Wo[(4 * i + 2) * 64 + h], yy0);
        yy1 = fmaf(o.w, Wo[(4 * i + 3) * 64 + h], yy1);
    }
    float y = yy0 + yy1;

    // tanh-approx GELU (JAX default approximate=True)
    float t3 = y + 0.044715f * y * y * y;
    float ge = 0.5f * y * (1.0f + tanhf(0.7978845608028654f * t3));

    out[g * 64 + h] = xres + ge;
}

// ==================== cooperative fused kernel ====================
// 512 blocks x 512 threads (2 blocks/CU co-residency -- wide margin).
// Stage A: blocks 0..3 build per-scene 16^3 grids; all blocks project 32 pts.
// grid.sync(). Stage B: 4096 waves x 4 queries (grid-sorted + XCD swizzle).
__global__ __launch_bounds__(NTHR, 4) void fused_kernel(
    const float* __restrict__ x, const float* __restrict__ pos,
    const float* __restrict__ Wq, const float* __restrict__ bq,
    const float* __restrict__ Wk, const float* __restrict__ bk,
    const float* __restrict__ Wv, const float* __restrict__ bv,
    const float* __restrict__ Wpe, const float* __restrict__ bpe,
    const float* __restrict__ Wpd, const float* __restrict__ bpd,
    const float* __restrict__ Wa, const float* __restrict__ ba,
    const float* __restrict__ Wo, const float* __restrict__ bo,
    float* __restrict__ qpe, float* __restrict__ kpe, float* __restrict__ vv,
    int* __restrict__ cell_start, float4* __restrict__ gpts,
    float* __restrict__ out)
{
    __shared__ SU sh;
    int tid = threadIdx.x, bid = blockIdx.x;
    int wv = tid >> 6, lane = tid & 63;

    // ---------------- Stage A1: grid build (blocks 0..3) ----------------
    if (bid < S_DIM) {
        const float4* g4 = (const float4*)(pos + (size_t)bid * N_PTS * 3);
        for (int i = tid; i < NCELL; i += NTHR) sh.gb.cnt[i] = 0;
        __syncthreads();

        int cell[8];
        #pragma unroll
        for (int u = 0; u < 2; ++u) {
            float4 a = g4[tid * 6 + u * 3 + 0];
            float4 b = g4[tid * 6 + u * 3 + 1];
            float4 c = g4[tid * 6 + u * 3 + 2];
            float xx[4] = {a.x, a.w, b.z, c.y};
            float yy[4] = {a.y, b.x, b.w, c.z};
            float zz[4] = {a.z, b.y, c.x, c.w};
            #pragma unroll
            for (int k = 0; k < 4; ++k) {
                int cx = min(GD - 1, max(0, (int)(xx[k] * 16.f)));
                int cy = min(GD - 1, max(0, (int)(yy[k] * 16.f)));
                int cz = min(GD - 1, max(0, (int)(zz[k] * 16.f)));
                cell[u * 4 + k] = (cx * GD + cy) * GD + cz;
                atomicAdd(&sh.gb.cnt[cell[u * 4 + k]], 1);
            }
        }
        __syncthreads();

        int c[8], pre[8], ts = 0;
        #pragma unroll
        for (int i = 0; i < 8; ++i) { c[i] = sh.gb.cnt[tid * 8 + i]; pre[i] = ts; ts += c[i]; }
        int inc = ts;
        #pragma unroll
        for (int off = 1; off < 64; off <<= 1) {
            int n = __shfl_up(inc, off, 64);
            if (lane >= off) inc += n;
        }
        if (lane == 63) sh.gb.wtot[wv] = inc;
        __syncthreads();
        if (wv == 0) {
            int v0 = (lane < 8) ? sh.gb.wtot[lane] : 0;
            int i2 = v0;
            #pragma unroll
            for (int off = 1; off < 8; off <<= 1) {
                int n = __shfl_up(i2, off, 64);
                if (lane >= off) i2 += n;
            }
            if (lane < 8) sh.gb.wtot[lane] = i2 - v0;   // exclusive
        }
        __syncthreads();
        int base = sh.gb.wtot[wv] + inc - ts;
        #pragma unroll
        for (int i = 0; i < 8; ++i) sh.gb.start[tid * 8 + i] = base + pre[i];
        if (tid == 0) sh.gb.start[NCELL] = N_PTS;
        __syncthreads();

        for (int i = tid; i < NCELL + 1; i += NTHR)
            cell_start[bid * CSTRIDE + i] = sh.gb.start[i];
        for (int i = tid; i < NCELL; i += NTHR) sh.gb.cnt[i] = 0;  // cursors
        __syncthreads();

        #pragma unroll
        for (int u = 0; u < 2; ++u) {
            float4 a = g4[tid * 6 + u * 3 + 0];
            float4 b = g4[tid * 6 + u * 3 + 1];
            float4 c = g4[tid * 6 + u * 3 + 2];
            float xx[4] = {a.x, a.w, b.z, c.y};
            float yy[4] = {a.y, b.x, b.w, c.z};
            float zz[4] = {a.z, b.y, c.x, c.w};
            #pragma unroll
            for (int k = 0; k < 4; ++k) {
                int cl = cell[u * 4 + k];
                int slot = sh.gb.start[cl] + atomicAdd(&sh.gb.cnt[cl], 1);
                gpts[(size_t)bid * N_PTS + slot] =
                    make_float4(xx[k], yy[k], zz[k],
                                __uint_as_float((unsigned)(tid * 8 + u * 4 + k)));
            }
        }
        __syncthreads();
    }

    // ------------- Stage A2: projections (all blocks, 32 pts) -------------
    {
        int g0 = bid * 32;
        ((float4*)sh.pj.xs)[tid] = ((const float4*)(x + (size_t)g0 * 64))[tid];
        if (tid < 24)
            ((float4*)sh.pj.psf)[tid] = ((const float4*)(pos + (size_t)g0 * 3))[tid];
        __syncthreads();

        int h = lane;
        int pb = wv * 4;
        float aq[4], ak[4], av[4];
        float bqh = bq[h], bkh = bk[h], bvh = bv[h];
        #pragma unroll
        for (int p = 0; p < 4; ++p) { aq[p] = bqh; ak[p] = bkh; av[p] = bvh; }
        #pragma unroll 8
        for (int f = 0; f < 64; ++f) {
            float wq = Wq[f * 64 + h];
            float wk = Wk[f * 64 + h];
            float wvv = Wv[f * 64 + h];
            #pragma unroll
            for (int p = 0; p < 4; ++p) {
                float xf = sh.pj.xs[pb + p][f];
                aq[p] = fmaf(xf, wq, aq[p]);
                ak[p] = fmaf(xf, wk, ak[p]);
                av[p] = fmaf(xf, wvv, av[p]);
            }
        }
        float wpe0 = Wpe[h], wpe1 = Wpe[64 + h], wpe2 = Wpe[128 + h], bpeh = bpe[h];
        #pragma unroll
        for (int p = 0; p < 4; ++p) {
            int pp = pb + p;
            float pe = fmaf(sh.pj.psf[pp * 3 + 0], wpe0,
                       fmaf(sh.pj.psf[pp * 3 + 1], wpe1,
                       fmaf(sh.pj.psf[pp * 3 + 2], wpe2, bpeh)));
            int gp = g0 + pp;
            qpe[gp * 64 + h] = aq[p] + pe;
            kpe[gp * 64 + h] = ak[p] + pe;
            vv[gp * 64 + h]  = av[p];
        }
    }

    __threadfence();
    cg::this_grid().sync();
    __threadfence();

    // ---------------- Stage B: KNN + attention, 4 queries/wave ----------------
    {
        int swzb = (bid & 7) * 64 + (bid >> 3);   // bijective XCD swizzle (512 blocks)
        int W = swzb * 8 + wv;                     // wave id in [0, 4096)

        float wa = Wa[lane], boh = bo[lane], bpdh = bpd[lane];
        float wpd0 = Wpd[lane], wpd1 = Wpd[64 + lane], wpd2 = Wpd[128 + lane];
        float ba0 = ba[0];

        #pragma unroll 1
        for (int qi = 0; qi < 4; ++qi) {
            knn_attn_query(W * 4 + qi, lane,
                           sh.at.buf[wv], sh.at.map[wv], sh.at.ridx[wv], sh.at.ohs[wv],
                           x, pos, cell_start, gpts,
                           wpd0, wpd1, wpd2, bpdh, wa, ba0, boh,
                           Wo, qpe, kpe, vv, out);
        }
    }
}

// ==================== fallback kernels (round-9 proven path) ====================

__global__ __launch_bounds__(1024) void pre_kernel(
    const float* __restrict__ x, const float* __restrict__ pos,
    const float* __restrict__ Wq, const float* __restrict__ bq,
    const float* __restrict__ Wk, const float* __restrict__ bk,
    const float* __restrict__ Wv, const float* __restrict__ bv,
    const float* __restrict__ Wpe, const float* __restrict__ bpe,
    float* __restrict__ qpe, float* __restrict__ kpe, float* __restrict__ vout,
    int* __restrict__ cell_start, float4* __restrict__ gpts)
{
    int tid = threadIdx.x;

    if (blockIdx.x < PROJ_BLKS) {
        __shared__ float xs[64][64];
        __shared__ float psf[192];
        int h = tid & 63;
        int wv = tid >> 6;
        int g0 = blockIdx.x * 64;

        ((float4*)xs)[tid] = ((const float4*)(x + (size_t)g0 * 64))[tid];
        if (tid < 48)
            ((float4*)psf)[tid] = ((const float4*)(pos + (size_t)g0 * 3))[tid];
        __syncthreads();

        int pbase = wv * 4;
        float aq[4], ak[4], av[4];
        #pragma unroll
        for (int p = 0; p < 4; ++p) { aq[p] = bq[h]; ak[p] = bk[h]; av[p] = bv[h]; }

        #pragma unroll 8
        for (int f = 0; f < 64; ++f) {
            float wq = Wq[f * 64 + h];
            float wk = Wk[f * 64 + h];
            float wvv = Wv[f * 64 + h];
            #pragma unroll
            for (int p = 0; p < 4; ++p) {
                float xf = xs[pbase + p][f];
                aq[p] = fmaf(xf, wq, aq[p]);
                ak[p] = fmaf(xf, wk, ak[p]);
                av[p] = fmaf(xf, wvv, av[p]);
            }
        }

        float wpe0 = Wpe[0 * 64 + h], wpe1 = Wpe[1 * 64 + h], wpe2 = Wpe[2 * 64 + h];
        float bpeh = bpe[h];
        #pragma unroll
        for (int p = 0; p < 4; ++p) {
            int pp = pbase + p;
            float pe = fmaf(psf[pp * 3 + 0], wpe0,
                       fmaf(psf[pp * 3 + 1], wpe1,
                       fmaf(psf[pp * 3 + 2], wpe2, bpeh)));
            int gp = g0 + pp;
            qpe[gp * 64 + h]  = aq[p] + pe;
            kpe[gp * 64 + h]  = ak[p] + pe;
            vout[gp * 64 + h] = av[p];
        }
    } else {
        __shared__ int cnt[NCELL];
        __shared__ int start[NCELL + 1];
        __shared__ int wtot[16];

        int s = blockIdx.x - PROJ_BLKS;
        const float* psrc = pos + (size_t)s * N_PTS * 3;

        for (int i = tid; i < NCELL; i += 1024) cnt[i] = 0;
        __syncthreads();

        const float4* g4 = (const float4*)psrc;
        float4 a = g4[tid * 3 + 0];
        float4 b = g4[tid * 3 + 1];
        float4 c4 = g4[tid * 3 + 2];
        float xx[4] = {a.x, a.w, b.z, c4.y};
        float yy[4] = {a.y, b.x, b.w, c4.z};
        float zz[4] = {a.z, b.y, c4.x, c4.w};
        int cell[4];
        #pragma unroll
        for (int k = 0; k < 4; ++k) {
            int cx = min(GD - 1, max(0, (int)(xx[k] * 16.0f)));
            int cy = min(GD - 1, max(0, (int)(yy[k] * 16.0f)));
            int cz = min(GD - 1, max(0, (int)(zz[k] * 16.0f)));
            cell[k] = (cx * GD + cy) * GD + cz;
            atomicAdd(&cnt[cell[k]], 1);
        }
        __syncthreads();

        int wv = tid >> 6, lane = tid & 63;
        int c0 = cnt[tid * 4 + 0], c1 = cnt[tid * 4 + 1];
        int c2 = cnt[tid * 4 + 2], c3 = cnt[tid * 4 + 3];
        int ts = c0 + c1 + c2 + c3;
        int inc = ts;
        #pragma unroll
        for (int off = 1; off < 64; off <<= 1) {
            int n = __shfl_up(inc, off, 64);
            if (lane >= off) inc += n;
        }
        if (lane == 63) wtot[wv] = inc;
        __syncthreads();
        if (wv == 0) {
            int v0 = (lane < 16) ? wtot[lane] : 0;
            int i2 = v0;
            #pragma unroll
            for (int off = 1; off < 16; off <<= 1) {
                int n = __shfl_up(i2, off, 64);
                if (lane >= off) i2 += n;
            }
            if (lane < 16) wtot[lane] = i2 - v0;
        }
        __syncthreads();
        int base = wtot[wv] + inc - ts;
        start[tid * 4 + 0] = base;
        start[tid * 4 + 1] = base + c0;
        start[tid * 4 + 2] = base + c0 + c1;
        start[tid * 4 + 3] = base + c0 + c1 + c2;
        if (tid == 0) start[NCELL] = N_PTS;
        __syncthreads();

        for (int i = tid; i < NCELL + 1; i += 1024)
            cell_start[s * CSTRIDE + i] = start[i];
        for (int i = tid; i < NCELL; i += 1024) cnt[i] = 0;
        __syncthreads();

        #pragma unroll
        for (int k = 0; k < 4; ++k) {
            int slot = start[cell[k]] + atomicAdd(&cnt[cell[k]], 1);
            gpts[(size_t)s * N_PTS + slot] =
                make_float4(xx[k], yy[k], zz[k],
                            __uint_as_float((unsigned)(tid * 4 + k)));
        }
    }
}

__global__ __launch_bounds__(512) void knn_attn_kernel(
    const float* __restrict__ x, const float* __restrict__ pos,
    const int* __restrict__ cell_start, const float4* __restrict__ gpts,
    const float* __restrict__ Wpd, const float* __restrict__ bpd,
    const float* __restrict__ Wa, const float* __restrict__ ba,
    const float* __restrict__ Wo, const float* __restrict__ bo,
    const float* __restrict__ qpe, const float* __restrict__ kpe,
    const float* __restrict__ v, float* __restrict__ out)
{
    __shared__ SAT sat;
    int tid = threadIdx.x;
    int wave = tid >> 6, lane = tid & 63;

    int bid = blockIdx.x;
    int swz = (bid & 7) * 256 + (bid >> 3);      // bijective XCD swizzle
    int qslot = swz * 8 + wave;

    float wa = Wa[lane], boh = bo[lane], bpdh = bpd[lane];
    float wpd0 = Wpd[lane], wpd1 = Wpd[64 + lane], wpd2 = Wpd[128 + lane];
    float ba0 = ba[0];

    knn_attn_query(qslot, lane,
                   sat.buf[wave], sat.map[wave], sat.ridx[wave], sat.ohs[wave],
                   x, pos, cell_start, gpts,
                   wpd0, wpd1, wpd2, bpdh, wa, ba0, boh,
                   Wo, qpe, kpe, v, out);
}

extern "C" void kernel_launch(void* const* d_in, const int* in_sizes, int n_in,
                              void* d_out, int out_size, void* d_ws, size_t ws_size,
                              hipStream_t stream) {
    const float* x   = (const float*)d_in[0];
    const float* pos = (const float*)d_in[1];
    const float* Wq  = (const float*)d_in[2];
    const float* bq  = (const float*)d_in[3];
    const float* Wk  = (const float*)d_in[4];
    const float* bk  = (const float*)d_in[5];
    const float* Wv  = (const float*)d_in[6];
    const float* bv  = (const float*)d_in[7];
    const float* Wpe = (const float*)d_in[8];
    const float* bpe = (const float*)d_in[9];
    const float* Wpd = (const float*)d_in[10];
    const float* bpd = (const float*)d_in[11];
    const float* Wa  = (const float*)d_in[12];
    const float* ba  = (const float*)d_in[13];
    const float* Wo  = (const float*)d_in[14];
    const float* bo  = (const float*)d_in[15];
    float* out = (float*)d_out;

    float* ws  = (float*)d_ws;
    float* qpe = ws;
    float* kpe = ws + (size_t)P_TOT * 64;
    float* vv  = ws + (size_t)2 * P_TOT * 64;
    int*   cstart = (int*)(ws + (size_t)3 * P_TOT * 64);   // 4*4097 ints
    float4* gpts = (float4*)(cstart + S_DIM * CSTRIDE);    // 16B-aligned

    void* args[] = {
        (void*)&x, (void*)&pos,
        (void*)&Wq, (void*)&bq, (void*)&Wk, (void*)&bk,
        (void*)&Wv, (void*)&bv, (void*)&Wpe, (void*)&bpe,
        (void*)&Wpd, (void*)&bpd, (void*)&Wa, (void*)&ba,
        (void*)&Wo, (void*)&bo,
        (void*)&qpe, (void*)&kpe, (void*)&vv,
        (void*)&cstart, (void*)&gpts, (void*)&out
    };
    hipError_t err = hipLaunchCooperativeKernel((const void*)fused_kernel,
                                                dim3(NBLK), dim3(NTHR), args, 0, stream);
    if (err != hipSuccess) {
        // deterministic fallback: proven two-kernel path
        pre_kernel<<<PROJ_BLKS + S_DIM, 1024, 0, stream>>>(
            x, pos, Wq, bq, Wk, bk, Wv, bv, Wpe, bpe, qpe, kpe, vv, cstart, gpts);
        knn_attn_kernel<<<P_TOT / 8, 512, 0, stream>>>(
            x, pos, cstart, gpts, Wpd, bpd, Wa, ba, Wo, bo, qpe, kpe, vv, out);
    }
}

// Round 12
// 83.186 us; speedup vs baseline: 4.9581x; 4.9581x over previous
//
#include <hip/hip_runtime.h>
#include <hip/hip_bf16.h>

#define S_DIM 4
#define N_PTS 4096
#define P_TOT (S_DIM * N_PTS)   // 16384
#define KNB 16

#define GD 16                    // grid dim per axis
#define NCELL (GD * GD * GD)     // 4096
#define CSTRIDE (NCELL + 1)
#define CAP 224                  // per-wave candidate buffer
#define MAPSZ 512                // per-wave gather source map
#define PROJ_BLKS 256            // 64 points per block, 4 per wave

__device__ __forceinline__ float readlane_f(float v, int lane) {
    return __uint_as_float(__builtin_amdgcn_readlane(__float_as_uint(v), lane));
}

// ---------------- Kernel 1: fused projections + grid build ----------------
__global__ __launch_bounds__(1024) void pre_kernel(
    const float* __restrict__ x, const float* __restrict__ pos,
    const float* __restrict__ Wq, const float* __restrict__ bq,
    const float* __restrict__ Wk, const float* __restrict__ bk,
    const float* __restrict__ Wv, const float* __restrict__ bv,
    const float* __restrict__ Wpe, const float* __restrict__ bpe,
    float* __restrict__ qpe, float* __restrict__ kpe, float* __restrict__ vout,
    int* __restrict__ cell_start, float4* __restrict__ gpts)
{
    int tid = threadIdx.x;

    if (blockIdx.x < PROJ_BLKS) {
        // ---------------- projection path ----------------
        __shared__ float xs[64][64];     // 16 KB
        __shared__ float psf[192];
        int h = tid & 63;
        int wv = tid >> 6;
        int g0 = blockIdx.x * 64;

        ((float4*)xs)[tid] = ((const float4*)(x + (size_t)g0 * 64))[tid];
        if (tid < 48)
            ((float4*)psf)[tid] = ((const float4*)(pos + (size_t)g0 * 3))[tid];
        __syncthreads();

        int pbase = wv * 4;
        float aq[4], ak[4], av[4];
        #pragma unroll
        for (int p = 0; p < 4; ++p) { aq[p] = bq[h]; ak[p] = bk[h]; av[p] = bv[h]; }

        #pragma unroll 8
        for (int f = 0; f < 64; ++f) {
            float wq = Wq[f * 64 + h];
            float wk = Wk[f * 64 + h];
            float wvv = Wv[f * 64 + h];
            #pragma unroll
            for (int p = 0; p < 4; ++p) {
                float xf = xs[pbase + p][f];
                aq[p] = fmaf(xf, wq, aq[p]);
                ak[p] = fmaf(xf, wk, ak[p]);
                av[p] = fmaf(xf, wvv, av[p]);
            }
        }

        float wpe0 = Wpe[0 * 64 + h], wpe1 = Wpe[1 * 64 + h], wpe2 = Wpe[2 * 64 + h];
        float bpeh = bpe[h];
        #pragma unroll
        for (int p = 0; p < 4; ++p) {
            int pp = pbase + p;
            float pe = fmaf(psf[pp * 3 + 0], wpe0,
                       fmaf(psf[pp * 3 + 1], wpe1,
                       fmaf(psf[pp * 3 + 2], wpe2, bpeh)));
            int gp = g0 + pp;
            qpe[gp * 64 + h]  = aq[p] + pe;
            kpe[gp * 64 + h]  = ak[p] + pe;
            vout[gp * 64 + h] = av[p];
        }
    } else {
        // ---------------- 16^3 grid build path ----------------
        __shared__ int cnt[NCELL];       // 16 KB
        __shared__ int start[NCELL + 1]; // 16 KB
        __shared__ int wtot[16];

        int s = blockIdx.x - PROJ_BLKS;
        const float* psrc = pos + (size_t)s * N_PTS * 3;

        for (int i = tid; i < NCELL; i += 1024) cnt[i] = 0;
        __syncthreads();

        const float4* g4 = (const float4*)psrc;
        float4 a = g4[tid * 3 + 0];
        float4 b = g4[tid * 3 + 1];
        float4 c4 = g4[tid * 3 + 2];
        float xx[4] = {a.x, a.w, b.z, c4.y};
        float yy[4] = {a.y, b.x, b.w, c4.z};
        float zz[4] = {a.z, b.y, c4.x, c4.w};
        int cell[4];
        #pragma unroll
        for (int k = 0; k < 4; ++k) {
            int cx = min(GD - 1, max(0, (int)(xx[k] * 16.0f)));
            int cy = min(GD - 1, max(0, (int)(yy[k] * 16.0f)));
            int cz = min(GD - 1, max(0, (int)(zz[k] * 16.0f)));
            cell[k] = (cx * GD + cy) * GD + cz;
            atomicAdd(&cnt[cell[k]], 1);
        }
        __syncthreads();

        // hierarchical exclusive scan of 4096 counts
        int wv = tid >> 6, lane = tid & 63;
        int c0 = cnt[tid * 4 + 0], c1 = cnt[tid * 4 + 1];
        int c2 = cnt[tid * 4 + 2], c3 = cnt[tid * 4 + 3];
        int ts = c0 + c1 + c2 + c3;
        int inc = ts;
        #pragma unroll
        for (int off = 1; off < 64; off <<= 1) {
            int n = __shfl_up(inc, off, 64);
            if (lane >= off) inc += n;
        }
        if (lane == 63) wtot[wv] = inc;
        __syncthreads();
        if (wv == 0) {
            int v0 = (lane < 16) ? wtot[lane] : 0;
            int i2 = v0;
            #pragma unroll
            for (int off = 1; off < 16; off <<= 1) {
                int n = __shfl_up(i2, off, 64);
                if (lane >= off) i2 += n;
            }
            if (lane < 16) wtot[lane] = i2 - v0;   // exclusive
        }
        __syncthreads();
        int base = wtot[wv] + inc - ts;
        start[tid * 4 + 0] = base;
        start[tid * 4 + 1] = base + c0;
        start[tid * 4 + 2] = base + c0 + c1;
        start[tid * 4 + 3] = base + c0 + c1 + c2;
        if (tid == 0) start[NCELL] = N_PTS;
        __syncthreads();

        for (int i = tid; i < NCELL + 1; i += 1024)
            cell_start[s * CSTRIDE + i] = start[i];
        for (int i = tid; i < NCELL; i += 1024) cnt[i] = 0;   // reuse as cursor
        __syncthreads();

        #pragma unroll
        for (int k = 0; k < 4; ++k) {
            int slot = start[cell[k]] + atomicAdd(&cnt[cell[k]], 1);
            gpts[(size_t)s * N_PTS + slot] =
                make_float4(xx[k], yy[k], zz[k],
                            __uint_as_float((unsigned)(tid * 4 + k)));
        }
    }
}

// Per-query exact KNN + attention body. All LDS pointers are wave-private.
__device__ __forceinline__ void knn_attn_query(
    int qslot, int lane,
    unsigned long long* mybuf, unsigned short* mymap, int* myridx, float* myohs,
    const float* __restrict__ x, const float* __restrict__ pos,
    const int* __restrict__ cell_start, const float4* __restrict__ gpts,
    float wpd0, float wpd1, float wpd2, float bpdh,
    float wa, float ba0, float boh,
    const float* __restrict__ Wo,
    const float* __restrict__ qpe, const float* __restrict__ kpe,
    const float* __restrict__ vv, float* __restrict__ out)
{
    int s = qslot >> 12;
    int sbase = s << 12;
    const int* cs = cell_start + s * CSTRIDE;
    const float4* gp = gpts + (size_t)sbase;

    float4 q4 = gp[qslot & (N_PTS - 1)];
    float qx = q4.x, qy = q4.y, qz = q4.z;
    int g = sbase + (int)__float_as_uint(q4.w);

    // early-issue phase-2 operands
    float qv   = qpe[g * 64 + lane];
    float xres = x[g * 64 + lane];

    // adaptive radius: target ~32 candidates incl. boundary truncation
    float bx = fminf(qx, 1.f - qx), by = fminf(qy, 1.f - qy), bz = fminf(qz, 1.f - qz);
    float r = 0.125f;
    #pragma unroll
    for (int it = 0; it < 2; ++it) {
        float ux = fminf(bx / r, 1.f), uy = fminf(by / r, 1.f), uz = fminf(bz / r, 1.f);
        float fx = 0.5f + 0.75f * ux - 0.25f * ux * ux * ux;
        float fy = 0.5f + 0.75f * uy - 0.25f * uy * uy * uy;
        float fz = 0.5f + 0.75f * uz - 0.25f * uz * uz * uz;
        float est = 17157.3f * r * r * r * fx * fy * fz;
        float sc = exp2f(0.3333333f * log2f(32.f / est));
        r = fminf(fmaxf(r * sc, 0.09f), 0.32f);
    }
    r = __uint_as_float(__builtin_amdgcn_readfirstlane(__float_as_uint(r)));

    unsigned long long lanemask_lt = (lane == 0) ? 0ull : (~0ull >> (64 - lane));

    int cnt = 0;
    for (int tries = 0; tries < 6; ++tries) {
        float B = r * r;
        float Bc = B * 1.0002f + 1e-7f;
        int xlo = max(0, (int)floorf((qx - r) * 16.f - 1e-4f));
        int xhi = min(GD - 1, (int)floorf((qx + r) * 16.f + 1e-4f));
        int ylo = max(0, (int)floorf((qy - r) * 16.f - 1e-4f));
        int yhi = min(GD - 1, (int)floorf((qy + r) * 16.f + 1e-4f));
        int nx = xhi - xlo + 1, ny = yhi - ylo + 1;
        int NC = __builtin_amdgcn_readfirstlane(nx * ny);
        float rcp_ny = 1.f / (float)ny;

        // protect previous map/buf reads before rewriting
        __builtin_amdgcn_wave_barrier();
        asm volatile("s_waitcnt lgkmcnt(0)" ::: "memory");

        // wave-parallel run-table -> direct source map
        int carry = 0;
        for (int c0 = 0; c0 < NC; c0 += 64) {
            int cidx = c0 + lane;
            bool vld = cidx < NC;
            int qd = (int)(((float)cidx + 0.5f) * rcp_ny);
            int iy = ylo + (cidx - qd * ny);
            int ix = xlo + qd;
            float x0 = (float)ix * 0.0625f;
            float ax = fmaxf(0.f, fmaxf(x0 - qx, qx - (x0 + 0.0625f)));
            float y0 = (float)iy * 0.0625f;
            float ay = fmaxf(0.f, fmaxf(y0 - qy, qy - (y0 + 0.0625f)));
            float rem = Bc - ax * ax - ay * ay;
            int lo = 0, len = 0;
            if (vld && rem > 0.f) {
                float zs = sqrtf(rem) + 1e-4f;
                int zl = max(0, (int)floorf((qz - zs) * 16.f));
                int zh = min(GD - 1, (int)floorf((qz + zs) * 16.f));
                int cb = (ix * GD + iy) * GD;
                lo = cs[cb + zl];
                len = cs[cb + zh + 1] - lo;
            }
            int inc2 = len;
            #pragma unroll
            for (int off = 1; off < 64; off <<= 1) {
                int n = __shfl_up(inc2, off, 64);
                if (lane >= off) inc2 += n;
            }
            int excl = carry + inc2 - len;
            for (int i = 0; i < len; ++i) {
                int d = excl + i;
                if (d < MAPSZ) mymap[d] = (unsigned short)(lo + i);
            }
            carry += __builtin_amdgcn_readlane(inc2, 63);
        }
        int T = carry;
        if (T > MAPSZ) { r = r * 0.72f; continue; }

        __builtin_amdgcn_wave_barrier();
        asm volatile("s_waitcnt lgkmcnt(0)" ::: "memory");

        // gather + compact
        cnt = 0;
        for (int p0 = 0; p0 < T; p0 += 64) {
            int pidx = p0 + lane;
            bool act = pidx < T;
            int src = mymap[act ? pidx : 0];
            float4 p = gp[src];
            float dx = qx - p.x, dy = qy - p.y, dz = qz - p.z;
            float d = fmaf(dx, dx, fmaf(dy, dy, dz * dz));
            bool pred = act && (d < B);
            unsigned long long m = __ballot(pred);
            if (pred) {
                int slot = cnt + __popcll(m & lanemask_lt);
                if (slot < CAP)
                    mybuf[slot] =
                        ((unsigned long long)__float_as_uint(d) << 32) |
                        (unsigned long long)__float_as_uint(p.w);
            }
            cnt += __popcll(m);
        }
        if (cnt >= KNB && cnt <= CAP) break;
        r = (cnt < KNB) ? r * 1.35f : r * 0.72f;
    }
    cnt = min(cnt, CAP);

    __builtin_amdgcn_wave_barrier();
    asm volatile("s_waitcnt lgkmcnt(0)" ::: "memory");

    // rank-count selection (exact jax.lax.top_k order)
    if (lane < KNB) myridx[lane] = 0;
    for (int bb = 0; bb < cnt; bb += 64) {
        int slot = bb + lane;
        unsigned long long my = (slot < cnt) ? mybuf[slot] : ~0ull;
        int rank = 0;
        for (int j = 0; j < cnt; ++j)
            rank += (mybuf[j] < my) ? 1 : 0;
        if (slot < cnt && rank < KNB)
            myridx[rank] = (int)(unsigned)(my & 0xFFFFFFFFull);
    }
    __builtin_amdgcn_wave_barrier();
    asm volatile("s_waitcnt lgkmcnt(0)" ::: "memory");
    int res = (lane < KNB) ? myridx[lane] : 0;

    // ---- attention (lane = h)
    int h = lane;
    float wh = qv * wa * 0.125f;   // / sqrt(64)

    int jidx[KNB];
    float t[KNB];
    #pragma unroll
    for (int k = 0; k < KNB; ++k) {
        int jj = sbase + __builtin_amdgcn_readlane(res, k);
        jidx[k] = jj;
        float rx = pos[jj * 3 + 0] - qx;
        float ry = pos[jj * 3 + 1] - qy;
        float rz = pos[jj * 3 + 2] - qz;
        float pd = fmaf(rx, wpd0, fmaf(ry, wpd1, fmaf(rz, wpd2, bpdh)));
        t[k] = wh * (kpe[jj * 64 + h] + pd);
    }

    // merged log-tree reduction: 16 vectors with 31 shfl
    #pragma unroll
    for (int kk = 0; kk < 8; ++kk) {
        float a = t[2 * kk]     + __shfl_xor(t[2 * kk],     32, 64);
        float b = t[2 * kk + 1] + __shfl_xor(t[2 * kk + 1], 32, 64);
        t[kk] = (h & 32) ? b : a;
    }
    #pragma unroll
    for (int kk = 0; kk < 4; ++kk) {
        float a = t[2 * kk]     + __shfl_xor(t[2 * kk],     16, 64);
        float b = t[2 * kk + 1] + __shfl_xor(t[2 * kk + 1], 16, 64);
        t[kk] = (h & 16) ? b : a;
    }
    #pragma unroll
    for (int kk = 0; kk < 2; ++kk) {
        float a = t[2 * kk]     + __shfl_xor(t[2 * kk],     8, 64);
        float b = t[2 * kk + 1] + __shfl_xor(t[2 * kk + 1], 8, 64);
        t[kk] = (h & 8) ? b : a;
    }
    {
        float a = t[0] + __shfl_xor(t[0], 4, 64);
        float b = t[1] + __shfl_xor(t[1], 4, 64);
        t[0] = (h & 4) ? b : a;
    }
    float rr = t[0];
    rr += __shfl_xor(rr, 2, 64);
    rr += __shfl_xor(rr, 1, 64);
    // lane holds logit of k = rev4(lane>>2)

    float lg = rr + ba0;
    float mx = lg;
    mx = fmaxf(mx, __shfl_xor(mx, 4, 64));
    mx = fmaxf(mx, __shfl_xor(mx, 8, 64));
    mx = fmaxf(mx, __shfl_xor(mx, 16, 64));
    mx = fmaxf(mx, __shfl_xor(mx, 32, 64));
    float e = expf(lg - mx);
    float sm = e;
    sm += __shfl_xor(sm, 4, 64);
    sm += __shfl_xor(sm, 8, 64);
    sm += __shfl_xor(sm, 16, 64);
    sm += __shfl_xor(sm, 32, 64);
    float wk_mine = e * (1.0f / sm);

    // PV: broadcast w_k from lane rev4(k)*4 (rev4 is an involution)
    const int rev[KNB] = {0, 8, 4, 12, 2, 10, 6, 14, 1, 9, 5, 13, 3, 11, 7, 15};
    float oh = 0.f;
    #pragma unroll
    for (int k = 0; k < KNB; ++k) {
        float wk = readlane_f(wk_mine, rev[k] << 2);
        oh = fmaf(wk, vv[jidx[k] * 64 + h], oh);
    }

    // Wo projection via LDS float4 broadcast reads
    myohs[h] = oh;
    __builtin_amdgcn_wave_barrier();
    asm volatile("s_waitcnt lgkmcnt(0)" ::: "memory");
    const float4* oh4 = (const float4*)myohs;
    float yy0 = boh, yy1 = 0.f;
    #pragma unroll
    for (int i = 0; i < 16; ++i) {
        float4 o = oh4[i];
        yy0 = fmaf(o.x, Wo[(4 * i + 0) * 64 + h], yy0);
        yy1 = fmaf(o.y, Wo[(4 * i + 1) * 64 + h], yy1);
        yy0 = fmaf(o.z, Wo[(4 * i + 2) * 64 + h], yy0);
        yy1 = fmaf(o.w, Wo[(4 * i + 3) * 64 + h], yy1);
    }
    float y = yy0 + yy1;

    // tanh-approx GELU (JAX default approximate=True)
    float t3 = y + 0.044715f * y * y * y;
    float ge = 0.5f * y * (1.0f + tanhf(0.7978845608028654f * t3));

    out[g * 64 + h] = xres + ge;
}

// ---------------- Kernel 2: fused exact-top16 + attention ----------------
// 8 waves/block, 2 queries per wave (grid-sorted order + XCD swizzle).
__global__ __launch_bounds__(512) void knn_attn_kernel(
    const float* __restrict__ x, const float* __restrict__ pos,
    const int* __restrict__ cell_start, const float4* __restrict__ gpts,
    const float* __restrict__ Wpd, const float* __restrict__ bpd,
    const float* __restrict__ Wa, const float* __restrict__ ba,
    const float* __restrict__ Wo, const float* __restrict__ bo,
    const float* __restrict__ qpe, const float* __restrict__ kpe,
    const float* __restrict__ v, float* __restrict__ out)
{
    __shared__ unsigned long long buf[8][CAP];     // 14 KB
    __shared__ unsigned short map[8][MAPSZ];       // 8 KB
    __shared__ int ridx[8][KNB];
    __shared__ float ohs[8][64];

    int tid = threadIdx.x;
    int wave = tid >> 6, lane = tid & 63;

    int bid = blockIdx.x;                          // 1024 blocks
    int swz = (bid & 7) * 128 + (bid >> 3);        // bijective XCD swizzle
    int W = swz * 8 + wave;                        // wave id in [0, 8192)

    float wa = Wa[lane], boh = bo[lane], bpdh = bpd[lane];
    float wpd0 = Wpd[lane], wpd1 = Wpd[64 + lane], wpd2 = Wpd[128 + lane];
    float ba0 = ba[0];

    #pragma unroll 1
    for (int qi = 0; qi < 2; ++qi) {
        knn_attn_query(W * 2 + qi, lane,
                       buf[wave], map[wave], ridx[wave], ohs[wave],
                       x, pos, cell_start, gpts,
                       wpd0, wpd1, wpd2, bpdh, wa, ba0, boh,
                       Wo, qpe, kpe, v, out);
    }
}

extern "C" void kernel_launch(void* const* d_in, const int* in_sizes, int n_in,
                              void* d_out, int out_size, void* d_ws, size_t ws_size,
                              hipStream_t stream) {
    const float* x   = (const float*)d_in[0];
    const float* pos = (const float*)d_in[1];
    const float* Wq  = (const float*)d_in[2];
    const float* bq  = (const float*)d_in[3];
    const float* Wk  = (const float*)d_in[4];
    const float* bk  = (const float*)d_in[5];
    const float* Wv  = (const float*)d_in[6];
    const float* bv  = (const float*)d_in[7];
    const float* Wpe = (const float*)d_in[8];
    const float* bpe = (const float*)d_in[9];
    const float* Wpd = (const float*)d_in[10];
    const float* bpd = (const float*)d_in[11];
    const float* Wa  = (const float*)d_in[12];
    const float* ba  = (const float*)d_in[13];
    const float* Wo  = (const float*)d_in[14];
    const float* bo  = (const float*)d_in[15];
    float* out = (float*)d_out;

    float* ws  = (float*)d_ws;
    float* qpe = ws;
    float* kpe = ws + (size_t)P_TOT * 64;
    float* vv  = ws + (size_t)2 * P_TOT * 64;
    int*   cstart = (int*)(ws + (size_t)3 * P_TOT * 64);   // 4*4097 ints
    float4* gpts = (float4*)(cstart + S_DIM * CSTRIDE);    // 16B-aligned

    pre_kernel<<<PROJ_BLKS + S_DIM, 1024, 0, stream>>>(
        x, pos, Wq, bq, Wk, bk, Wv, bv, Wpe, bpe, qpe, kpe, vv, cstart, gpts);
    knn_attn_kernel<<<P_TOT / 16, 512, 0, stream>>>(
        x, pos, cstart, gpts, Wpd, bpd, Wa, ba, Wo, bo, qpe, kpe, vv, out);
}

// Round 13
// 63.015 us; speedup vs baseline: 6.5451x; 1.3201x over previous
//
#include <hip/hip_runtime.h>
#include <hip/hip_bf16.h>

#define S_DIM 4
#define N_PTS 4096
#define P_TOT (S_DIM * N_PTS)   // 16384
#define KNB 16

#define GD 16                    // grid dim per axis
#define NCELL (GD * GD * GD)     // 4096
#define CSTRIDE (NCELL + 1)
#define CAP 224                  // per-wave candidate buffer
#define MAPSZ 512                // per-wave gather source map
#define PROJ_BLKS 256            // 64 points per block, 4 per wave

__device__ __forceinline__ float readlane_f(float v, int lane) {
    return __uint_as_float(__builtin_amdgcn_readlane(__float_as_uint(v), lane));
}

// adaptive radius targeting ~24 candidates after boundary truncation
__device__ __forceinline__ float radius_for(float qx, float qy, float qz) {
    float bx = fminf(qx, 1.f - qx), by = fminf(qy, 1.f - qy), bz = fminf(qz, 1.f - qz);
    float r = 0.125f;
    #pragma unroll
    for (int it = 0; it < 2; ++it) {
        float ux = fminf(bx / r, 1.f), uy = fminf(by / r, 1.f), uz = fminf(bz / r, 1.f);
        float fx = 0.5f + 0.75f * ux - 0.25f * ux * ux * ux;
        float fy = 0.5f + 0.75f * uy - 0.25f * uy * uy * uy;
        float fz = 0.5f + 0.75f * uz - 0.25f * uz * uz * uz;
        float est = 17157.3f * r * r * r * fx * fy * fz;
        float sc = exp2f(0.3333333f * log2f(24.f / est));
        r = fminf(fmaxf(r * sc, 0.09f), 0.32f);
    }
    return r;
}

// ---------------- Kernel 1: fused projections + grid build ----------------
__global__ __launch_bounds__(1024) void pre_kernel(
    const float* __restrict__ x, const float* __restrict__ pos,
    const float* __restrict__ Wq, const float* __restrict__ bq,
    const float* __restrict__ Wk, const float* __restrict__ bk,
    const float* __restrict__ Wv, const float* __restrict__ bv,
    const float* __restrict__ Wpe, const float* __restrict__ bpe,
    float* __restrict__ qpe, float* __restrict__ kpe, float* __restrict__ vout,
    int* __restrict__ cell_start, float4* __restrict__ gpts,
    float* __restrict__ rad)
{
    int tid = threadIdx.x;

    if (blockIdx.x < PROJ_BLKS) {
        // ---------------- projection path ----------------
        __shared__ float xs[64][64];     // 16 KB
        __shared__ float psf[192];
        int h = tid & 63;
        int wv = tid >> 6;
        int g0 = blockIdx.x * 64;

        ((float4*)xs)[tid] = ((const float4*)(x + (size_t)g0 * 64))[tid];
        if (tid < 48)
            ((float4*)psf)[tid] = ((const float4*)(pos + (size_t)g0 * 3))[tid];
        __syncthreads();

        int pbase = wv * 4;
        float aq[4], ak[4], av[4];
        #pragma unroll
        for (int p = 0; p < 4; ++p) { aq[p] = bq[h]; ak[p] = bk[h]; av[p] = bv[h]; }

        #pragma unroll 8
        for (int f = 0; f < 64; ++f) {
            float wq = Wq[f * 64 + h];
            float wk = Wk[f * 64 + h];
            float wvv = Wv[f * 64 + h];
            #pragma unroll
            for (int p = 0; p < 4; ++p) {
                float xf = xs[pbase + p][f];
                aq[p] = fmaf(xf, wq, aq[p]);
                ak[p] = fmaf(xf, wk, ak[p]);
                av[p] = fmaf(xf, wvv, av[p]);
            }
        }

        float wpe0 = Wpe[0 * 64 + h], wpe1 = Wpe[1 * 64 + h], wpe2 = Wpe[2 * 64 + h];
        float bpeh = bpe[h];
        #pragma unroll
        for (int p = 0; p < 4; ++p) {
            int pp = pbase + p;
            float pe = fmaf(psf[pp * 3 + 0], wpe0,
                       fmaf(psf[pp * 3 + 1], wpe1,
                       fmaf(psf[pp * 3 + 2], wpe2, bpeh)));
            int gp = g0 + pp;
            qpe[gp * 64 + h]  = aq[p] + pe;
            kpe[gp * 64 + h]  = ak[p] + pe;
            vout[gp * 64 + h] = av[p];
        }
    } else {
        // ---------------- 16^3 grid build path ----------------
        __shared__ int cnt[NCELL];       // 16 KB
        __shared__ int start[NCELL + 1]; // 16 KB
        __shared__ int wtot[16];

        int s = blockIdx.x - PROJ_BLKS;
        const float* psrc = pos + (size_t)s * N_PTS * 3;

        for (int i = tid; i < NCELL; i += 1024) cnt[i] = 0;
        __syncthreads();

        const float4* g4 = (const float4*)psrc;
        float4 a = g4[tid * 3 + 0];
        float4 b = g4[tid * 3 + 1];
        float4 c4 = g4[tid * 3 + 2];
        float xx[4] = {a.x, a.w, b.z, c4.y};
        float yy[4] = {a.y, b.x, b.w, c4.z};
        float zz[4] = {a.z, b.y, c4.x, c4.w};
        int cell[4];
        #pragma unroll
        for (int k = 0; k < 4; ++k) {
            int cx = min(GD - 1, max(0, (int)(xx[k] * 16.0f)));
            int cy = min(GD - 1, max(0, (int)(yy[k] * 16.0f)));
            int cz = min(GD - 1, max(0, (int)(zz[k] * 16.0f)));
            cell[k] = (cx * GD + cy) * GD + cz;
            atomicAdd(&cnt[cell[k]], 1);
        }
        __syncthreads();

        // hierarchical exclusive scan of 4096 counts
        int wv = tid >> 6, lane = tid & 63;
        int c0 = cnt[tid * 4 + 0], c1 = cnt[tid * 4 + 1];
        int c2 = cnt[tid * 4 + 2], c3 = cnt[tid * 4 + 3];
        int ts = c0 + c1 + c2 + c3;
        int inc = ts;
        #pragma unroll
        for (int off = 1; off < 64; off <<= 1) {
            int n = __shfl_up(inc, off, 64);
            if (lane >= off) inc += n;
        }
        if (lane == 63) wtot[wv] = inc;
        __syncthreads();
        if (wv == 0) {
            int v0 = (lane < 16) ? wtot[lane] : 0;
            int i2 = v0;
            #pragma unroll
            for (int off = 1; off < 16; off <<= 1) {
                int n = __shfl_up(i2, off, 64);
                if (lane >= off) i2 += n;
            }
            if (lane < 16) wtot[lane] = i2 - v0;   // exclusive
        }
        __syncthreads();
        int base = wtot[wv] + inc - ts;
        start[tid * 4 + 0] = base;
        start[tid * 4 + 1] = base + c0;
        start[tid * 4 + 2] = base + c0 + c1;
        start[tid * 4 + 3] = base + c0 + c1 + c2;
        if (tid == 0) start[NCELL] = N_PTS;
        __syncthreads();

        for (int i = tid; i < NCELL + 1; i += 1024)
            cell_start[s * CSTRIDE + i] = start[i];
        for (int i = tid; i < NCELL; i += 1024) cnt[i] = 0;   // reuse as cursor
        __syncthreads();

        #pragma unroll
        for (int k = 0; k < 4; ++k) {
            int slot = start[cell[k]] + atomicAdd(&cnt[cell[k]], 1);
            gpts[(size_t)s * N_PTS + slot] =
                make_float4(xx[k], yy[k], zz[k],
                            __uint_as_float((unsigned)(tid * 4 + k)));
            rad[(size_t)s * N_PTS + slot] = radius_for(xx[k], yy[k], zz[k]);
        }
    }
}

// ---------------- Kernel 2: fused exact-top16 + attention ----------------
// One wave per query (grid-sorted order + XCD swizzle). Phase 1: radius r
// precomputed per slot (target ~24 candidates); z-column runs intersecting
// ball(r) expanded into a direct LDS source map; ballot-compact d<r^2 keys
// (dist<<32|origidx); rank-count selection (exact jax.lax.top_k order).
// Retry grows/shrinks r if cnt outside [16,CAP] or map overflows. Phase 2
// (lane=h): merged log-tree logit reduction, 1 exp/lane softmax, PV via
// readlane, Wo via LDS float4 reads, GELU, residual.
__global__ __launch_bounds__(512) void knn_attn_kernel(
    const float* __restrict__ x, const float* __restrict__ pos,
    const int* __restrict__ cell_start, const float4* __restrict__ gpts,
    const float* __restrict__ rad,
    const float* __restrict__ Wpd, const float* __restrict__ bpd,
    const float* __restrict__ Wa, const float* __restrict__ ba,
    const float* __restrict__ Wo, const float* __restrict__ bo,
    const float* __restrict__ qpe, const float* __restrict__ kpe,
    const float* __restrict__ v, float* __restrict__ out)
{
    __shared__ unsigned long long buf[8][CAP];     // 14 KB
    __shared__ unsigned short map[8][MAPSZ];       // 8 KB
    __shared__ int ridx[8][KNB];
    __shared__ float ohs[8][64];

    int tid = threadIdx.x;
    int wave = tid >> 6, lane = tid & 63;

    int bid = blockIdx.x;
    int swz = (bid & 7) * 256 + (bid >> 3);      // bijective XCD swizzle
    int qslot = swz * 8 + wave;
    int s = qslot >> 12;
    int sbase = s << 12;
    const int* cs = cell_start + s * CSTRIDE;
    const float4* gp = gpts + (size_t)sbase;
    unsigned long long* mybuf = buf[wave];
    unsigned short* mymap = map[wave];

    float4 q4 = gp[qslot & (N_PTS - 1)];
    float qx = q4.x, qy = q4.y, qz = q4.z;
    int g = sbase + (int)__float_as_uint(q4.w);

    // early-issue phase-2 operands (latency hidden under phase 1)
    float qv   = qpe[g * 64 + lane];
    float xres = x[g * 64 + lane];
    float wa   = Wa[lane];
    float boh  = bo[lane];
    float bpdh = bpd[lane];
    float wpd0 = Wpd[lane], wpd1 = Wpd[64 + lane], wpd2 = Wpd[128 + lane];
    float ba0  = ba[0];

    // precomputed adaptive radius
    float r = rad[qslot];
    r = __uint_as_float(__builtin_amdgcn_readfirstlane(__float_as_uint(r)));

    unsigned long long lanemask_lt = (lane == 0) ? 0ull : (~0ull >> (64 - lane));

    int cnt = 0;
    for (int tries = 0; tries < 6; ++tries) {
        float B = r * r;
        float Bc = B * 1.0002f + 1e-7f;   // conservative cull bound
        int xlo = max(0, (int)floorf((qx - r) * 16.f - 1e-4f));
        int xhi = min(GD - 1, (int)floorf((qx + r) * 16.f + 1e-4f));
        int ylo = max(0, (int)floorf((qy - r) * 16.f - 1e-4f));
        int yhi = min(GD - 1, (int)floorf((qy + r) * 16.f + 1e-4f));
        int nx = xhi - xlo + 1, ny = yhi - ylo + 1;
        int NC = __builtin_amdgcn_readfirstlane(nx * ny);
        float rcp_ny = 1.f / (float)ny;

        // protect previous-iteration map reads before rewriting
        __builtin_amdgcn_wave_barrier();
        asm volatile("s_waitcnt lgkmcnt(0)" ::: "memory");

        // ---- wave-parallel run-table build -> direct source map
        int carry = 0;
        for (int c0 = 0; c0 < NC; c0 += 64) {
            int cidx = c0 + lane;
            bool vld = cidx < NC;
            int qd = (int)(((float)cidx + 0.5f) * rcp_ny);
            int iy = ylo + (cidx - qd * ny);
            int ix = xlo + qd;
            float x0 = (float)ix * 0.0625f;
            float ax = fmaxf(0.f, fmaxf(x0 - qx, qx - (x0 + 0.0625f)));
            float y0 = (float)iy * 0.0625f;
            float ay = fmaxf(0.f, fmaxf(y0 - qy, qy - (y0 + 0.0625f)));
            float rem = Bc - ax * ax - ay * ay;
            int lo = 0, len = 0;
            if (vld && rem > 0.f) {
                float zs = sqrtf(rem) + 1e-4f;
                int zl = max(0, (int)floorf((qz - zs) * 16.f));
                int zh = min(GD - 1, (int)floorf((qz + zs) * 16.f));
                int cb = (ix * GD + iy) * GD;
                lo = cs[cb + zl];
                len = cs[cb + zh + 1] - lo;
            }
            int inc2 = len;
            #pragma unroll
            for (int off = 1; off < 64; off <<= 1) {
                int n = __shfl_up(inc2, off, 64);
                if (lane >= off) inc2 += n;
            }
            int excl = carry + inc2 - len;
            for (int i = 0; i < len; ++i) {
                int d = excl + i;
                if (d < MAPSZ) mymap[d] = (unsigned short)(lo + i);
            }
            carry += __builtin_amdgcn_readlane(inc2, 63);
        }
        int T = carry;
        if (T > MAPSZ) { r = r * 0.72f; continue; }   // overflow -> shrink

        __builtin_amdgcn_wave_barrier();
        asm volatile("s_waitcnt lgkmcnt(0)" ::: "memory");

        // ---- gather + compact (one independent LDS read per point)
        cnt = 0;
        for (int p0 = 0; p0 < T; p0 += 64) {
            int pidx = p0 + lane;
            bool act = pidx < T;
            int src = mymap[act ? pidx : 0];
            float4 p = gp[src];
            float dx = qx - p.x, dy = qy - p.y, dz = qz - p.z;
            float d = fmaf(dx, dx, fmaf(dy, dy, dz * dz));
            bool pred = act && (d < B);
            unsigned long long m = __ballot(pred);
            if (pred) {
                int slot = cnt + __popcll(m & lanemask_lt);
                if (slot < CAP)
                    mybuf[slot] =
                        ((unsigned long long)__float_as_uint(d) << 32) |
                        (unsigned long long)__float_as_uint(p.w);
            }
            cnt += __popcll(m);
        }
        if (cnt >= KNB && cnt <= CAP) break;
        r = (cnt < KNB) ? r * 1.35f : r * 0.72f;
    }
    cnt = min(cnt, CAP);

    __builtin_amdgcn_wave_barrier();
    asm volatile("s_waitcnt lgkmcnt(0)" ::: "memory");

    // ---- rank-count selection (exact top-k order)
    if (lane < KNB) ridx[wave][lane] = 0;
    for (int bb = 0; bb < cnt; bb += 64) {
        int slot = bb + lane;
        unsigned long long my = (slot < cnt) ? mybuf[slot] : ~0ull;
        int rank = 0;
        for (int j = 0; j < cnt; ++j)
            rank += (mybuf[j] < my) ? 1 : 0;
        if (slot < cnt && rank < KNB)
            ridx[wave][rank] = (int)(unsigned)(my & 0xFFFFFFFFull);
    }
    __builtin_amdgcn_wave_barrier();
    asm volatile("s_waitcnt lgkmcnt(0)" ::: "memory");
    int res = (lane < KNB) ? ridx[wave][lane] : 0;

    // ---------------- Phase 2: attention (lane = h) ----------------
    int h = lane;
    float wh = qv * wa * 0.125f;   // / sqrt(64)

    int jidx[KNB];
    float t[KNB];
    #pragma unroll
    for (int k = 0; k < KNB; ++k) {
        int jj = sbase + __builtin_amdgcn_readlane(res, k);
        jidx[k] = jj;
        float rx = pos[jj * 3 + 0] - qx;
        float ry = pos[jj * 3 + 1] - qy;
        float rz = pos[jj * 3 + 2] - qz;
        float pd = fmaf(rx, wpd0, fmaf(ry, wpd1, fmaf(rz, wpd2, bpdh)));
        t[k] = wh * (kpe[jj * 64 + h] + pd);
    }

    // merged log-tree reduction: 16 vectors reduced with 31 shfl
    #pragma unroll
    for (int kk = 0; kk < 8; ++kk) {
        float a = t[2 * kk]     + __shfl_xor(t[2 * kk],     32, 64);
        float b = t[2 * kk + 1] + __shfl_xor(t[2 * kk + 1], 32, 64);
        t[kk] = (h & 32) ? b : a;
    }
    #pragma unroll
    for (int kk = 0; kk < 4; ++kk) {
        float a = t[2 * kk]     + __shfl_xor(t[2 * kk],     16, 64);
        float b = t[2 * kk + 1] + __shfl_xor(t[2 * kk + 1], 16, 64);
        t[kk] = (h & 16) ? b : a;
    }
    #pragma unroll
    for (int kk = 0; kk < 2; ++kk) {
        float a = t[2 * kk]     + __shfl_xor(t[2 * kk],     8, 64);
        float b = t[2 * kk + 1] + __shfl_xor(t[2 * kk + 1], 8, 64);
        t[kk] = (h & 8) ? b : a;
    }
    {
        float a = t[0] + __shfl_xor(t[0], 4, 64);
        float b = t[1] + __shfl_xor(t[1], 4, 64);
        t[0] = (h & 4) ? b : a;
    }
    float rr = t[0];
    rr += __shfl_xor(rr, 2, 64);
    rr += __shfl_xor(rr, 1, 64);
    // lane holds logit of k = rev4(lane>>2)

    float lg = rr + ba0;
    float mx = lg;
    mx = fmaxf(mx, __shfl_xor(mx, 4, 64));
    mx = fmaxf(mx, __shfl_xor(mx, 8, 64));
    mx = fmaxf(mx, __shfl_xor(mx, 16, 64));
    mx = fmaxf(mx, __shfl_xor(mx, 32, 64));
    float e = expf(lg - mx);
    float sm = e;
    sm += __shfl_xor(sm, 4, 64);
    sm += __shfl_xor(sm, 8, 64);
    sm += __shfl_xor(sm, 16, 64);
    sm += __shfl_xor(sm, 32, 64);
    float wk_mine = e * (1.0f / sm);

    // PV: broadcast w_k from lane rev4(k)*4 (rev4 is an involution)
    const int rev[KNB] = {0, 8, 4, 12, 2, 10, 6, 14, 1, 9, 5, 13, 3, 11, 7, 15};
    float oh = 0.f;
    #pragma unroll
    for (int k = 0; k < KNB; ++k) {
        float wk = readlane_f(wk_mine, rev[k] << 2);
        oh = fmaf(wk, v[jidx[k] * 64 + h], oh);
    }

    // Wo projection via LDS float4 broadcast reads (2 accumulator chains)
    ohs[wave][h] = oh;
    __builtin_amdgcn_wave_barrier();
    asm volatile("s_waitcnt lgkmcnt(0)" ::: "memory");
    const float4* oh4 = (const float4*)ohs[wave];
    float yy0 = boh, yy1 = 0.f;
    #pragma unroll
    for (int i = 0; i < 16; ++i) {
        float4 o = oh4[i];
        yy0 = fmaf(o.x, Wo[(4 * i + 0) * 64 + h], yy0);
        yy1 = fmaf(o.y, Wo[(4 * i + 1) * 64 + h], yy1);
        yy0 = fmaf(o.z, Wo[(4 * i + 2) * 64 + h], yy0);
        yy1 = fmaf(o.w, Wo[(4 * i + 3) * 64 + h], yy1);
    }
    float y = yy0 + yy1;

    // tanh-approx GELU (JAX default approximate=True)
    float t3 = y + 0.044715f * y * y * y;
    float ge = 0.5f * y * (1.0f + tanhf(0.7978845608028654f * t3));

    out[g * 64 + h] = xres + ge;
}

extern "C" void kernel_launch(void* const* d_in, const int* in_sizes, int n_in,
                              void* d_out, int out_size, void* d_ws, size_t ws_size,
                              hipStream_t stream) {
    const float* x   = (const float*)d_in[0];
    const float* pos = (const float*)d_in[1];
    const float* Wq  = (const float*)d_in[2];
    const float* bq  = (const float*)d_in[3];
    const float* Wk  = (const float*)d_in[4];
    const float* bk  = (const float*)d_in[5];
    const float* Wv  = (const float*)d_in[6];
    const float* bv  = (const float*)d_in[7];
    const float* Wpe = (const float*)d_in[8];
    const float* bpe = (const float*)d_in[9];
    const float* Wpd = (const float*)d_in[10];
    const float* bpd = (const float*)d_in[11];
    const float* Wa  = (const float*)d_in[12];
    const float* ba  = (const float*)d_in[13];
    const float* Wo  = (const float*)d_in[14];
    const float* bo  = (const float*)d_in[15];
    float* out = (float*)d_out;

    float* ws  = (float*)d_ws;
    float* qpe = ws;
    float* kpe = ws + (size_t)P_TOT * 64;
    float* vv  = ws + (size_t)2 * P_TOT * 64;
    int*   cstart = (int*)(ws + (size_t)3 * P_TOT * 64);   // 4*4097 ints
    float4* gpts = (float4*)(cstart + S_DIM * CSTRIDE);    // 16B-aligned
    float* radp = (float*)(gpts + P_TOT);                  // 16384 floats

    pre_kernel<<<PROJ_BLKS + S_DIM, 1024, 0, stream>>>(
        x, pos, Wq, bq, Wk, bk, Wv, bv, Wpe, bpe, qpe, kpe, vv, cstart, gpts, radp);
    knn_attn_kernel<<<P_TOT / 8, 512, 0, stream>>>(
        x, pos, cstart, gpts, radp, Wpd, bpd, Wa, ba, Wo, bo, qpe, kpe, vv, out);
}

// Round 14
// 61.791 us; speedup vs baseline: 6.6748x; 1.0198x over previous
//
#include <hip/hip_runtime.h>
#include <hip/hip_bf16.h>

#define S_DIM 4
#define N_PTS 4096
#define P_TOT (S_DIM * N_PTS)   // 16384
#define KNB 16

#define GD 16                    // grid dim per axis
#define NCELL (GD * GD * GD)     // 4096
#define CSTRIDE (NCELL + 1)
#define CAP 224                  // per-wave candidate buffer
#define MAPSZ 512                // per-wave gather source map
#define PROJ_BLKS 256            // 64 points per block, 4 per wave

__device__ __forceinline__ float readlane_f(float v, int lane) {
    return __uint_as_float(__builtin_amdgcn_readlane(__float_as_uint(v), lane));
}

// ---------------- Kernel 1: fused projections + grid build ----------------
__global__ __launch_bounds__(1024) void pre_kernel(
    const float* __restrict__ x, const float* __restrict__ pos,
    const float* __restrict__ Wq, const float* __restrict__ bq,
    const float* __restrict__ Wk, const float* __restrict__ bk,
    const float* __restrict__ Wv, const float* __restrict__ bv,
    const float* __restrict__ Wpe, const float* __restrict__ bpe,
    float* __restrict__ qpe, float* __restrict__ kpe, float* __restrict__ vout,
    int* __restrict__ cell_start, float4* __restrict__ gpts)
{
    int tid = threadIdx.x;

    if (blockIdx.x < PROJ_BLKS) {
        // ---------------- projection path ----------------
        __shared__ float xs[64][64];     // 16 KB
        __shared__ float psf[192];
        int h = tid & 63;
        int wv = tid >> 6;
        int g0 = blockIdx.x * 64;

        ((float4*)xs)[tid] = ((const float4*)(x + (size_t)g0 * 64))[tid];
        if (tid < 48)
            ((float4*)psf)[tid] = ((const float4*)(pos + (size_t)g0 * 3))[tid];
        __syncthreads();

        int pbase = wv * 4;
        float aq[4], ak[4], av[4];
        #pragma unroll
        for (int p = 0; p < 4; ++p) { aq[p] = bq[h]; ak[p] = bk[h]; av[p] = bv[h]; }

        #pragma unroll 8
        for (int f = 0; f < 64; ++f) {
            float wq = Wq[f * 64 + h];
            float wk = Wk[f * 64 + h];
            float wvv = Wv[f * 64 + h];
            #pragma unroll
            for (int p = 0; p < 4; ++p) {
                float xf = xs[pbase + p][f];
                aq[p] = fmaf(xf, wq, aq[p]);
                ak[p] = fmaf(xf, wk, ak[p]);
                av[p] = fmaf(xf, wvv, av[p]);
            }
        }

        float wpe0 = Wpe[0 * 64 + h], wpe1 = Wpe[1 * 64 + h], wpe2 = Wpe[2 * 64 + h];
        float bpeh = bpe[h];
        #pragma unroll
        for (int p = 0; p < 4; ++p) {
            int pp = pbase + p;
            float pe = fmaf(psf[pp * 3 + 0], wpe0,
                       fmaf(psf[pp * 3 + 1], wpe1,
                       fmaf(psf[pp * 3 + 2], wpe2, bpeh)));
            int gp = g0 + pp;
            qpe[gp * 64 + h]  = aq[p] + pe;
            kpe[gp * 64 + h]  = ak[p] + pe;
            vout[gp * 64 + h] = av[p];
        }
    } else {
        // ---------------- 16^3 grid build path ----------------
        __shared__ int cnt[NCELL];       // 16 KB
        __shared__ int start[NCELL + 1]; // 16 KB
        __shared__ int wtot[16];

        int s = blockIdx.x - PROJ_BLKS;
        const float* psrc = pos + (size_t)s * N_PTS * 3;

        for (int i = tid; i < NCELL; i += 1024) cnt[i] = 0;
        __syncthreads();

        const float4* g4 = (const float4*)psrc;
        float4 a = g4[tid * 3 + 0];
        float4 b = g4[tid * 3 + 1];
        float4 c4 = g4[tid * 3 + 2];
        float xx[4] = {a.x, a.w, b.z, c4.y};
        float yy[4] = {a.y, b.x, b.w, c4.z};
        float zz[4] = {a.z, b.y, c4.x, c4.w};
        int cell[4];
        #pragma unroll
        for (int k = 0; k < 4; ++k) {
            int cx = min(GD - 1, max(0, (int)(xx[k] * 16.0f)));
            int cy = min(GD - 1, max(0, (int)(yy[k] * 16.0f)));
            int cz = min(GD - 1, max(0, (int)(zz[k] * 16.0f)));
            cell[k] = (cx * GD + cy) * GD + cz;
            atomicAdd(&cnt[cell[k]], 1);
        }
        __syncthreads();

        // hierarchical exclusive scan of 4096 counts
        int wv = tid >> 6, lane = tid & 63;
        int c0 = cnt[tid * 4 + 0], c1 = cnt[tid * 4 + 1];
        int c2 = cnt[tid * 4 + 2], c3 = cnt[tid * 4 + 3];
        int ts = c0 + c1 + c2 + c3;
        int inc = ts;
        #pragma unroll
        for (int off = 1; off < 64; off <<= 1) {
            int n = __shfl_up(inc, off, 64);
            if (lane >= off) inc += n;
        }
        if (lane == 63) wtot[wv] = inc;
        __syncthreads();
        if (wv == 0) {
            int v0 = (lane < 16) ? wtot[lane] : 0;
            int i2 = v0;
            #pragma unroll
            for (int off = 1; off < 16; off <<= 1) {
                int n = __shfl_up(i2, off, 64);
                if (lane >= off) i2 += n;
            }
            if (lane < 16) wtot[lane] = i2 - v0;   // exclusive
        }
        __syncthreads();
        int base = wtot[wv] + inc - ts;
        start[tid * 4 + 0] = base;
        start[tid * 4 + 1] = base + c0;
        start[tid * 4 + 2] = base + c0 + c1;
        start[tid * 4 + 3] = base + c0 + c1 + c2;
        if (tid == 0) start[NCELL] = N_PTS;
        __syncthreads();

        for (int i = tid; i < NCELL + 1; i += 1024)
            cell_start[s * CSTRIDE + i] = start[i];
        for (int i = tid; i < NCELL; i += 1024) cnt[i] = 0;   // reuse as cursor
        __syncthreads();

        #pragma unroll
        for (int k = 0; k < 4; ++k) {
            int slot = start[cell[k]] + atomicAdd(&cnt[cell[k]], 1);
            gpts[(size_t)s * N_PTS + slot] =
                make_float4(xx[k], yy[k], zz[k],
                            __uint_as_float((unsigned)(tid * 4 + k)));
        }
    }
}

// ---------------- Kernel 2: fused exact-top16 + attention ----------------
// One wave per query (grid-sorted order + XCD swizzle). Phase 1: adaptive
// radius r (inline, target ~24 candidates incl. boundary truncation);
// z-column runs intersecting ball(r) expanded into a direct LDS source map;
// ballot-compact d<r^2 keys (dist<<32|origidx); rank-count selection (exact
// jax.lax.top_k order). Retry grows/shrinks r if cnt outside [16,CAP] or map
// overflows. Phase 2 (lane=h): merged log-tree logit reduction, 1 exp/lane
// softmax, PV via readlane, Wo via LDS float4 reads, GELU, residual.
__global__ __launch_bounds__(512) void knn_attn_kernel(
    const float* __restrict__ x, const float* __restrict__ pos,
    const int* __restrict__ cell_start, const float4* __restrict__ gpts,
    const float* __restrict__ Wpd, const float* __restrict__ bpd,
    const float* __restrict__ Wa, const float* __restrict__ ba,
    const float* __restrict__ Wo, const float* __restrict__ bo,
    const float* __restrict__ qpe, const float* __restrict__ kpe,
    const float* __restrict__ v, float* __restrict__ out)
{
    __shared__ unsigned long long buf[8][CAP];     // 14 KB
    __shared__ unsigned short map[8][MAPSZ];       // 8 KB
    __shared__ int ridx[8][KNB];
    __shared__ float ohs[8][64];

    int tid = threadIdx.x;
    int wave = tid >> 6, lane = tid & 63;

    int bid = blockIdx.x;
    int swz = (bid & 7) * 256 + (bid >> 3);      // bijective XCD swizzle
    int qslot = swz * 8 + wave;
    int s = qslot >> 12;
    int sbase = s << 12;
    const int* cs = cell_start + s * CSTRIDE;
    const float4* gp = gpts + (size_t)sbase;
    unsigned long long* mybuf = buf[wave];
    unsigned short* mymap = map[wave];

    float4 q4 = gp[qslot & (N_PTS - 1)];
    float qx = q4.x, qy = q4.y, qz = q4.z;
    int g = sbase + (int)__float_as_uint(q4.w);

    // early-issue phase-2 operands (latency hidden under phase 1)
    float qv   = qpe[g * 64 + lane];
    float xres = x[g * 64 + lane];
    float wa   = Wa[lane];
    float boh  = bo[lane];
    float bpdh = bpd[lane];
    float wpd0 = Wpd[lane], wpd1 = Wpd[64 + lane], wpd2 = Wpd[128 + lane];
    float ba0  = ba[0];

    // ---- adaptive radius: target ~24 candidates after boundary truncation
    float bx = fminf(qx, 1.f - qx), by = fminf(qy, 1.f - qy), bz = fminf(qz, 1.f - qz);
    float r = 0.125f;
    #pragma unroll
    for (int it = 0; it < 2; ++it) {
        float ux = fminf(bx / r, 1.f), uy = fminf(by / r, 1.f), uz = fminf(bz / r, 1.f);
        float fx = 0.5f + 0.75f * ux - 0.25f * ux * ux * ux;
        float fy = 0.5f + 0.75f * uy - 0.25f * uy * uy * uy;
        float fz = 0.5f + 0.75f * uz - 0.25f * uz * uz * uz;
        float est = 17157.3f * r * r * r * fx * fy * fz;
        float sc = exp2f(0.3333333f * log2f(24.f / est));
        r = fminf(fmaxf(r * sc, 0.09f), 0.32f);
    }
    r = __uint_as_float(__builtin_amdgcn_readfirstlane(__float_as_uint(r)));

    unsigned long long lanemask_lt = (lane == 0) ? 0ull : (~0ull >> (64 - lane));

    int cnt = 0;
    for (int tries = 0; tries < 6; ++tries) {
        float B = r * r;
        float Bc = B * 1.0002f + 1e-7f;   // conservative cull bound
        int xlo = max(0, (int)floorf((qx - r) * 16.f - 1e-4f));
        int xhi = min(GD - 1, (int)floorf((qx + r) * 16.f + 1e-4f));
        int ylo = max(0, (int)floorf((qy - r) * 16.f - 1e-4f));
        int yhi = min(GD - 1, (int)floorf((qy + r) * 16.f + 1e-4f));
        int nx = xhi - xlo + 1, ny = yhi - ylo + 1;
        int NC = __builtin_amdgcn_readfirstlane(nx * ny);
        float rcp_ny = 1.f / (float)ny;

        // protect previous-iteration map reads before rewriting
        __builtin_amdgcn_wave_barrier();
        asm volatile("s_waitcnt lgkmcnt(0)" ::: "memory");

        // ---- wave-parallel run-table build -> direct source map
        int carry = 0;
        for (int c0 = 0; c0 < NC; c0 += 64) {
            int cidx = c0 + lane;
            bool vld = cidx < NC;
            int qd = (int)(((float)cidx + 0.5f) * rcp_ny);
            int iy = ylo + (cidx - qd * ny);
            int ix = xlo + qd;
            float x0 = (float)ix * 0.0625f;
            float ax = fmaxf(0.f, fmaxf(x0 - qx, qx - (x0 + 0.0625f)));
            float y0 = (float)iy * 0.0625f;
            float ay = fmaxf(0.f, fmaxf(y0 - qy, qy - (y0 + 0.0625f)));
            float rem = Bc - ax * ax - ay * ay;
            int lo = 0, len = 0;
            if (vld && rem > 0.f) {
                float zs = sqrtf(rem) + 1e-4f;
                int zl = max(0, (int)floorf((qz - zs) * 16.f));
                int zh = min(GD - 1, (int)floorf((qz + zs) * 16.f));
                int cb = (ix * GD + iy) * GD;
                lo = cs[cb + zl];
                len = cs[cb + zh + 1] - lo;
            }
            int inc2 = len;
            #pragma unroll
            for (int off = 1; off < 64; off <<= 1) {
                int n = __shfl_up(inc2, off, 64);
                if (lane >= off) inc2 += n;
            }
            int excl = carry + inc2 - len;
            for (int i = 0; i < len; ++i) {
                int d = excl + i;
                if (d < MAPSZ) mymap[d] = (unsigned short)(lo + i);
            }
            carry += __builtin_amdgcn_readlane(inc2, 63);
        }
        int T = carry;
        if (T > MAPSZ) { r = r * 0.72f; continue; }   // overflow -> shrink

        __builtin_amdgcn_wave_barrier();
        asm volatile("s_waitcnt lgkmcnt(0)" ::: "memory");

        // ---- gather + compact (one independent LDS read per point)
        cnt = 0;
        for (int p0 = 0; p0 < T; p0 += 64) {
            int pidx = p0 + lane;
            bool act = pidx < T;
            int src = mymap[act ? pidx : 0];
            float4 p = gp[src];
            float dx = qx - p.x, dy = qy - p.y, dz = qz - p.z;
            float d = fmaf(dx, dx, fmaf(dy, dy, dz * dz));
            bool pred = act && (d < B);
            unsigned long long m = __ballot(pred);
            if (pred) {
                int slot = cnt + __popcll(m & lanemask_lt);
                if (slot < CAP)
                    mybuf[slot] =
                        ((unsigned long long)__float_as_uint(d) << 32) |
                        (unsigned long long)__float_as_uint(p.w);
            }
            cnt += __popcll(m);
        }
        if (cnt >= KNB && cnt <= CAP) break;
        r = (cnt < KNB) ? r * 1.35f : r * 0.72f;
    }
    cnt = min(cnt, CAP);

    __builtin_amdgcn_wave_barrier();
    asm volatile("s_waitcnt lgkmcnt(0)" ::: "memory");

    // ---- rank-count selection (exact top-k order)
    if (lane < KNB) ridx[wave][lane] = 0;
    for (int bb = 0; bb < cnt; bb += 64) {
        int slot = bb + lane;
        unsigned long long my = (slot < cnt) ? mybuf[slot] : ~0ull;
        int rank = 0;
        for (int j = 0; j < cnt; ++j)
            rank += (mybuf[j] < my) ? 1 : 0;
        if (slot < cnt && rank < KNB)
            ridx[wave][rank] = (int)(unsigned)(my & 0xFFFFFFFFull);
    }
    __builtin_amdgcn_wave_barrier();
    asm volatile("s_waitcnt lgkmcnt(0)" ::: "memory");
    int res = (lane < KNB) ? ridx[wave][lane] : 0;

    // ---------------- Phase 2: attention (lane = h) ----------------
    int h = lane;
    float wh = qv * wa * 0.125f;   // / sqrt(64)

    int jidx[KNB];
    float t[KNB];
    #pragma unroll
    for (int k = 0; k < KNB; ++k) {
        int jj = sbase + __builtin_amdgcn_readlane(res, k);
        jidx[k] = jj;
        float rx = pos[jj * 3 + 0] - qx;
        float ry = pos[jj * 3 + 1] - qy;
        float rz = pos[jj * 3 + 2] - qz;
        float pd = fmaf(rx, wpd0, fmaf(ry, wpd1, fmaf(rz, wpd2, bpdh)));
        t[k] = wh * (kpe[jj * 64 + h] + pd);
    }

    // merged log-tree reduction: 16 vectors reduced with 31 shfl
    #pragma unroll
    for (int kk = 0; kk < 8; ++kk) {
        float a = t[2 * kk]     + __shfl_xor(t[2 * kk],     32, 64);
        float b = t[2 * kk + 1] + __shfl_xor(t[2 * kk + 1], 32, 64);
        t[kk] = (h & 32) ? b : a;
    }
    #pragma unroll
    for (int kk = 0; kk < 4; ++kk) {
        float a = t[2 * kk]     + __shfl_xor(t[2 * kk],     16, 64);
        float b = t[2 * kk + 1] + __shfl_xor(t[2 * kk + 1], 16, 64);
        t[kk] = (h & 16) ? b : a;
    }
    #pragma unroll
    for (int kk = 0; kk < 2; ++kk) {
        float a = t[2 * kk]     + __shfl_xor(t[2 * kk],     8, 64);
        float b = t[2 * kk + 1] + __shfl_xor(t[2 * kk + 1], 8, 64);
        t[kk] = (h & 8) ? b : a;
    }
    {
        float a = t[0] + __shfl_xor(t[0], 4, 64);
        float b = t[1] + __shfl_xor(t[1], 4, 64);
        t[0] = (h & 4) ? b : a;
    }
    float rr = t[0];
    rr += __shfl_xor(rr, 2, 64);
    rr += __shfl_xor(rr, 1, 64);
    // lane holds logit of k = rev4(lane>>2)

    float lg = rr + ba0;
    float mx = lg;
    mx = fmaxf(mx, __shfl_xor(mx, 4, 64));
    mx = fmaxf(mx, __shfl_xor(mx, 8, 64));
    mx = fmaxf(mx, __shfl_xor(mx, 16, 64));
    mx = fmaxf(mx, __shfl_xor(mx, 32, 64));
    float e = expf(lg - mx);
    float sm = e;
    sm += __shfl_xor(sm, 4, 64);
    sm += __shfl_xor(sm, 8, 64);
    sm += __shfl_xor(sm, 16, 64);
    sm += __shfl_xor(sm, 32, 64);
    float wk_mine = e * (1.0f / sm);

    // PV: broadcast w_k from lane rev4(k)*4 (rev4 is an involution)
    const int rev[KNB] = {0, 8, 4, 12, 2, 10, 6, 14, 1, 9, 5, 13, 3, 11, 7, 15};
    float oh = 0.f;
    #pragma unroll
    for (int k = 0; k < KNB; ++k) {
        float wk = readlane_f(wk_mine, rev[k] << 2);
        oh = fmaf(wk, v[jidx[k] * 64 + h], oh);
    }

    // Wo projection via LDS float4 broadcast reads (2 accumulator chains)
    ohs[wave][h] = oh;
    __builtin_amdgcn_wave_barrier();
    asm volatile("s_waitcnt lgkmcnt(0)" ::: "memory");
    const float4* oh4 = (const float4*)ohs[wave];
    float yy0 = boh, yy1 = 0.f;
    #pragma unroll
    for (int i = 0; i < 16; ++i) {
        float4 o = oh4[i];
        yy0 = fmaf(o.x, Wo[(4 * i + 0) * 64 + h], yy0);
        yy1 = fmaf(o.y, Wo[(4 * i + 1) * 64 + h], yy1);
        yy0 = fmaf(o.z, Wo[(4 * i + 2) * 64 + h], yy0);
        yy1 = fmaf(o.w, Wo[(4 * i + 3) * 64 + h], yy1);
    }
    float y = yy0 + yy1;

    // tanh-approx GELU (JAX default approximate=True)
    float t3 = y + 0.044715f * y * y * y;
    float ge = 0.5f * y * (1.0f + tanhf(0.7978845608028654f * t3));

    out[g * 64 + h] = xres + ge;
}

extern "C" void kernel_launch(void* const* d_in, const int* in_sizes, int n_in,
                              void* d_out, int out_size, void* d_ws, size_t ws_size,
                              hipStream_t stream) {
    const float* x   = (const float*)d_in[0];
    const float* pos = (const float*)d_in[1];
    const float* Wq  = (const float*)d_in[2];
    const float* bq  = (const float*)d_in[3];
    const float* Wk  = (const float*)d_in[4];
    const float* bk  = (const float*)d_in[5];
    const float* Wv  = (const float*)d_in[6];
    const float* bv  = (const float*)d_in[7];
    const float* Wpe = (const float*)d_in[8];
    const float* bpe = (const float*)d_in[9];
    const float* Wpd = (const float*)d_in[10];
    const float* bpd = (const float*)d_in[11];
    const float* Wa  = (const float*)d_in[12];
    const float* ba  = (const float*)d_in[13];
    const float* Wo  = (const float*)d_in[14];
    const float* bo  = (const float*)d_in[15];
    float* out = (float*)d_out;

    float* ws  = (float*)d_ws;
    float* qpe = ws;
    float* kpe = ws + (size_t)P_TOT * 64;
    float* vv  = ws + (size_t)2 * P_TOT * 64;
    int*   cstart = (int*)(ws + (size_t)3 * P_TOT * 64);   // 4*4097 ints
    float4* gpts = (float4*)(cstart + S_DIM * CSTRIDE);    // 16B-aligned

    pre_kernel<<<PROJ_BLKS + S_DIM, 1024, 0, stream>>>(
        x, pos, Wq, bq, Wk, bk, Wv, bv, Wpe, bpe, qpe, kpe, vv, cstart, gpts);
    knn_attn_kernel<<<P_TOT / 8, 512, 0, stream>>>(
        x, pos, cstart, gpts, Wpd, bpd, Wa, ba, Wo, bo, qpe, kpe, vv, out);
}